// Round 4
// baseline (11214.690 us; speedup 1.0000x reference)
//
#include <hip/hip_runtime.h>
#include <hip/hip_bf16.h>

#define Nn 4096
#define Ff 256
#define NCLS 16
#define Ne 65536
#define TSZ 262144   // hash slots (2^18), load factor <= 0.25
#define NF (Nn*Ff)

typedef unsigned int u32;

// ---------------- device-global workspace (no d_ws dependence) ----------------
__device__ float g_yA[NF], g_yB[NF], g_zA[NF], g_zB[NF], g_t1[NF], g_T1[NF];
__device__ float g_G[Ff*Ff];
__device__ float g_col[Ff];
__device__ float g_P[Ne], g_cc[Ne];
__device__ float g_hV[TSZ];
__device__ u32   g_hK[TSZ], g_slot[Ne];

// ---------------- small utility kernels ----------------
__global__ __launch_bounds__(256) void k_copy(float* dst, const float* src, int n){
    int i = blockIdx.x*256 + threadIdx.x;
    if (i < n) dst[i] = src[i];
}
__global__ __launch_bounds__(256) void k_zero(float* p, int n){
    int i = blockIdx.x*256 + threadIdx.x;
    if (i < n) p[i] = 0.f;
}
__global__ __launch_bounds__(256) void k_fillc(float* p, float v, int n){
    int i = blockIdx.x*256 + threadIdx.x;
    if (i < n) p[i] = v;
}
__global__ __launch_bounds__(256) void k_hkeys_clear(u32* K){
    int i = blockIdx.x*256 + threadIdx.x;
    if (i < TSZ) K[i] = 0xFFFFFFFFu;
}
__global__ __launch_bounds__(256) void k_hsetup(u32* K, u32* slot, const int* ei, const int* ej){
    int e = blockIdx.x*256 + threadIdx.x;
    if (e >= Ne) return;
    u32 key = ((u32)ei[e] << 12) | (u32)ej[e];
    u32 h = (key * 2654435761u) & (TSZ-1);
    for (;;){
        u32 old = atomicCAS(&K[h], 0xFFFFFFFFu, key);
        if (old == 0xFFFFFFFFu || old == key){ slot[e] = h; break; }
        h = (h+1) & (TSZ-1);
    }
}
__global__ __launch_bounds__(256) void k_hacc(float* V, const float* P, const u32* slot){
    int e = blockIdx.x*256 + threadIdx.x;
    if (e < Ne) atomicAdd(&V[slot[e]], P[e]);
}

// ---------------- G[256,256] += A^T B over k-chunk (split-K atomics) ----------------
__global__ __launch_bounds__(256) void k_gram(float* __restrict__ G, const float* __restrict__ A,
                                              const float* __restrict__ B){
    const int tid = threadIdx.x, tx = tid & 15, ty = tid >> 4;
    const int i0 = blockIdx.x*64, j0 = blockIdx.y*64, kc = blockIdx.z*256;
    __shared__ float As[32][65], Bs[32][65];
    float acc[4][4] = {};
    for (int ks = 0; ks < 8; ++ks){
        const int k0 = kc + ks*32;
        for (int l = tid; l < 2048; l += 256){
            int k = l >> 6, c = l & 63;
            As[k][c] = A[(size_t)(k0+k)*Ff + i0 + c];
            Bs[k][c] = B[(size_t)(k0+k)*Ff + j0 + c];
        }
        __syncthreads();
        #pragma unroll 8
        for (int k = 0; k < 32; ++k){
            float a0=As[k][ty*4+0],a1=As[k][ty*4+1],a2=As[k][ty*4+2],a3=As[k][ty*4+3];
            float b0=Bs[k][tx*4+0],b1=Bs[k][tx*4+1],b2=Bs[k][tx*4+2],b3=Bs[k][tx*4+3];
            acc[0][0]+=a0*b0; acc[0][1]+=a0*b1; acc[0][2]+=a0*b2; acc[0][3]+=a0*b3;
            acc[1][0]+=a1*b0; acc[1][1]+=a1*b1; acc[1][2]+=a1*b2; acc[1][3]+=a1*b3;
            acc[2][0]+=a2*b0; acc[2][1]+=a2*b1; acc[2][2]+=a2*b2; acc[2][3]+=a2*b3;
            acc[3][0]+=a3*b0; acc[3][1]+=a3*b1; acc[3][2]+=a3*b2; acc[3][3]+=a3*b3;
        }
        __syncthreads();
    }
    #pragma unroll
    for (int r = 0; r < 4; ++r)
        #pragma unroll
        for (int c = 0; c < 4; ++c)
            atomicAdd(&G[(size_t)(i0+ty*4+r)*Ff + j0+tx*4+c], acc[r][c]);
}

__global__ __launch_bounds__(256) void k_colsum(float* col, const float* __restrict__ y){
    int j = threadIdx.x;
    int r0 = blockIdx.x*64;
    float s = 0.f;
    for (int i = 0; i < 64; ++i) s += y[(size_t)(r0+i)*Ff + j];
    atomicAdd(&col[j], s);
}

// ---------------- out[4096,256] from Y[4096,256] @ G[256,256] ----------------
// MODE 0: out = base - Y@G ; MODE 1: out = col[j] - Y@G ; MODE 2: out = Y@G
template<int MODE>
__global__ __launch_bounds__(256) void k_yg(float* __restrict__ out, const float* __restrict__ Y,
                                            const float* __restrict__ G, const float* __restrict__ base){
    const int tid = threadIdx.x, tx = tid & 15, ty = tid >> 4;
    const int j0 = blockIdx.x*64, i0 = blockIdx.y*64;
    __shared__ float Ys[64][33];
    __shared__ __align__(16) float Gs[32][68];
    float acc[4][4] = {};
    for (int ks = 0; ks < 8; ++ks){
        const int k0 = ks*32;
        for (int l = tid; l < 2048; l += 256){
            int i = l >> 5, k = l & 31;
            Ys[i][k] = Y[(size_t)(i0+i)*Ff + k0+k];
        }
        for (int l = tid; l < 2048; l += 256){
            int k = l >> 6, j = l & 63;
            Gs[k][j] = G[(size_t)(k0+k)*Ff + j0+j];
        }
        __syncthreads();
        #pragma unroll 4
        for (int k = 0; k < 32; ++k){
            float a0=Ys[ty*4+0][k],a1=Ys[ty*4+1][k],a2=Ys[ty*4+2][k],a3=Ys[ty*4+3][k];
            float4 b = *(const float4*)(&Gs[k][tx*4]);
            acc[0][0]+=a0*b.x; acc[0][1]+=a0*b.y; acc[0][2]+=a0*b.z; acc[0][3]+=a0*b.w;
            acc[1][0]+=a1*b.x; acc[1][1]+=a1*b.y; acc[1][2]+=a1*b.z; acc[1][3]+=a1*b.w;
            acc[2][0]+=a2*b.x; acc[2][1]+=a2*b.y; acc[2][2]+=a2*b.z; acc[2][3]+=a2*b.w;
            acc[3][0]+=a3*b.x; acc[3][1]+=a3*b.y; acc[3][2]+=a3*b.z; acc[3][3]+=a3*b.w;
        }
        __syncthreads();
    }
    #pragma unroll
    for (int r = 0; r < 4; ++r)
        #pragma unroll
        for (int c = 0; c < 4; ++c){
            int gr = i0+ty*4+r, gc = j0+tx*4+c;
            size_t idx = (size_t)gr*Ff + gc;
            if constexpr (MODE == 0) out[idx] = base[idx] - acc[r][c];
            if constexpr (MODE == 1) out[idx] = base[gc] - acc[r][c];
            if constexpr (MODE == 2) out[idx] = acc[r][c];
        }
}

// ---------------- dense 4096x4096(f32) @ X[4096,256](f32) ----------------
// V 0: t1 += mEA@X        (mEA = 0.5*EA*w22, row-major)
// V 1: t1 -= mEA^T@X
// V 2: out = feat + 0.5*sigmoid(w1@X)
// V 3: out = zp - mEA@X
template<int V>
__global__ __launch_bounds__(256) void k_dense(float* __restrict__ out,
        const float* __restrict__ W, const float* __restrict__ w22,
        const float* __restrict__ X, const float* __restrict__ featp, const float* __restrict__ zp){
    const int tid = threadIdx.x, tx = tid & 15, ty = tid >> 4;
    const int j0 = blockIdx.x*64, i0 = blockIdx.y*64;
    __shared__ float As[64][33];
    __shared__ __align__(16) float Xs[32][68];
    float acc[4][4] = {};
    for (int ks = 0; ks < 128; ++ks){
        const int k0 = ks*32;
        if constexpr (V == 1){
            for (int l = tid; l < 2048; l += 256){
                int k = l >> 6, i = l & 63;           // read row (k0+k), cols (i0+i): coalesced
                size_t idx = (size_t)(k0+k)*Nn + (i0+i);
                As[i][k] = 0.5f * W[idx] * w22[idx];
            }
        } else {
            for (int l = tid; l < 2048; l += 256){
                int i = l >> 5, k = l & 31;
                size_t idx = (size_t)(i0+i)*Nn + (k0+k);
                float v = W[idx];
                if constexpr (V == 0 || V == 3) v *= 0.5f * w22[idx];
                As[i][k] = v;
            }
        }
        for (int l = tid; l < 2048; l += 256){
            int k = l >> 6, j = l & 63;
            Xs[k][j] = X[(size_t)(k0+k)*Ff + j0+j];
        }
        __syncthreads();
        #pragma unroll 4
        for (int k = 0; k < 32; ++k){
            float a0=As[ty*4+0][k],a1=As[ty*4+1][k],a2=As[ty*4+2][k],a3=As[ty*4+3][k];
            float4 b = *(const float4*)(&Xs[k][tx*4]);
            acc[0][0]+=a0*b.x; acc[0][1]+=a0*b.y; acc[0][2]+=a0*b.z; acc[0][3]+=a0*b.w;
            acc[1][0]+=a1*b.x; acc[1][1]+=a1*b.y; acc[1][2]+=a1*b.z; acc[1][3]+=a1*b.w;
            acc[2][0]+=a2*b.x; acc[2][1]+=a2*b.y; acc[2][2]+=a2*b.z; acc[2][3]+=a2*b.w;
            acc[3][0]+=a3*b.x; acc[3][1]+=a3*b.y; acc[3][2]+=a3*b.z; acc[3][3]+=a3*b.w;
        }
        __syncthreads();
    }
    #pragma unroll
    for (int r = 0; r < 4; ++r)
        #pragma unroll
        for (int c = 0; c < 4; ++c){
            int gr = i0+ty*4+r, gc = j0+tx*4+c;
            size_t idx = (size_t)gr*Ff + gc;
            if constexpr (V == 0) out[idx] += acc[r][c];
            if constexpr (V == 1) out[idx] -= acc[r][c];
            if constexpr (V == 2) out[idx] = featp[idx] + 0.5f*(1.f/(1.f+expf(-acc[r][c])));
            if constexpr (V == 3) out[idx] = zp[idx] - acc[r][c];
        }
}

// ---------------- sparse scatters (one wave per edge) ----------------
__global__ __launch_bounds__(256) void k_sparseT(float* __restrict__ t1, const float* __restrict__ y,
        const float* __restrict__ c, const float* __restrict__ P,
        const int* __restrict__ ei, const int* __restrict__ ej, int useM){
    int e = blockIdx.x*4 + (threadIdx.x >> 6);
    int lane = threadIdx.x & 63;
    int i = ei[e], j = ej[e];
    float ce = c[e];
    #pragma unroll
    for (int q = 0; q < 4; ++q){
        int f = lane + q*64;
        atomicAdd(&t1[(size_t)i*Ff + f], ce * y[(size_t)j*Ff + f]);
    }
    if (useM){
        float pe = -0.5f * P[e];
        #pragma unroll
        for (int q = 0; q < 4; ++q){
            int f = lane + q*64;
            atomicAdd(&t1[(size_t)j*Ff + f], pe * y[(size_t)i*Ff + f]);
        }
    }
}
__global__ __launch_bounds__(256) void k_sparseZ(float* __restrict__ zn, const float* __restrict__ z,
        const float* __restrict__ c, const int* __restrict__ ei, const int* __restrict__ ej){
    int e = blockIdx.x*4 + (threadIdx.x >> 6);
    int lane = threadIdx.x & 63;
    int i = ei[e], j = ej[e];
    float ce = c[e];
    #pragma unroll
    for (int q = 0; q < 4; ++q){
        int f = lane + q*64;
        atomicAdd(&zn[(size_t)i*Ff + f], -ce * z[(size_t)j*Ff + f]);
    }
}

// ---------------- P_e = ||z_i - z_j|| * val_e ----------------
__global__ __launch_bounds__(256) void k_p(float* __restrict__ P, const float* __restrict__ z,
        const int* __restrict__ ei, const int* __restrict__ ej, const float* __restrict__ ev){
    int e = blockIdx.x*4 + (threadIdx.x >> 6);
    int lane = threadIdx.x & 63;
    int i = ei[e], j = ej[e];
    float s = 0.f;
    #pragma unroll
    for (int q = 0; q < 4; ++q){
        int f = lane + q*64;
        float d = z[(size_t)i*Ff + f] - z[(size_t)j*Ff + f];
        s += d*d;
    }
    #pragma unroll
    for (int o = 32; o; o >>= 1) s += __shfl_xor(s, o);
    if (lane == 0) P[e] = sqrtf(s) * ev[e];
}

// ---------------- c_e = val_e * (dot(y_i,y_j) - 0.5*M_ij) ----------------
__global__ __launch_bounds__(256) void k_ep(float* __restrict__ c, const float* __restrict__ y,
        const int* __restrict__ ei, const int* __restrict__ ej, const float* __restrict__ ev,
        const float* __restrict__ V, const u32* __restrict__ slot){
    int e = blockIdx.x*4 + (threadIdx.x >> 6);
    int lane = threadIdx.x & 63;
    int i = ei[e], j = ej[e];
    float s = 0.f;
    #pragma unroll
    for (int q = 0; q < 4; ++q){
        int f = lane + q*64;
        s += y[(size_t)i*Ff + f] * y[(size_t)j*Ff + f];
    }
    #pragma unroll
    for (int o = 32; o; o >>= 1) s += __shfl_xor(s, o);
    if (lane == 0) c[e] = ev[e] * (s - 0.5f * V[slot[e]]);
}

// ---------------- normalize + concat + linear + log_softmax (overflow-safe) ----------------
__global__ __launch_bounds__(256) void k_head(float* __restrict__ out, const float* __restrict__ y,
                                              const float* __restrict__ z, const float* __restrict__ w2w,
                                              const float* __restrict__ w2b){
    const int node = blockIdx.x, t = threadIdx.x;
    float yv = y[(size_t)node*Ff + t], zv = z[(size_t)node*Ff + t];
    float yc = fminf(fmaxf(yv, -1e37f), 1e37f);
    float zc = fminf(fmaxf(zv, -1e37f), 1e37f);
    __shared__ float sy[256], sz[256];
    sy[t] = fabsf(yc); sz[t] = fabsf(zc);
    __syncthreads();
    for (int s = 128; s; s >>= 1){ if (t < s){ sy[t]=fmaxf(sy[t],sy[t+s]); sz[t]=fmaxf(sz[t],sz[t+s]); } __syncthreads(); }
    float my_ = fmaxf(sy[0], 1e-30f), mz_ = fmaxf(sz[0], 1e-30f);
    __syncthreads();
    float ysc = yc/my_, zsc = zc/mz_;
    sy[t] = ysc*ysc; sz[t] = zsc*zsc;
    __syncthreads();
    for (int s = 128; s; s >>= 1){ if (t < s){ sy[t]+=sy[t+s]; sz[t]+=sz[t+s]; } __syncthreads(); }
    float ny = fmaxf(my_*sqrtf(sy[0]), 1e-12f);
    float nz = fmaxf(mz_*sqrtf(sz[0]), 1e-12f);
    float ynv = yc/ny, znv = zc/nz;
    float acc[NCLS];
    #pragma unroll
    for (int cc = 0; cc < NCLS; ++cc)
        acc[cc] = znv*w2w[t*NCLS+cc] + ynv*w2w[(Ff+t)*NCLS+cc];
    __shared__ float red[NCLS][257];
    #pragma unroll
    for (int cc = 0; cc < NCLS; ++cc) red[cc][t] = acc[cc];
    __syncthreads();
    for (int s = 128; s; s >>= 1){
        if (t < s){
            #pragma unroll
            for (int cc = 0; cc < NCLS; ++cc) red[cc][t] += red[cc][t+s];
        }
        __syncthreads();
    }
    __shared__ float lg[NCLS];
    __shared__ float ml[2];
    if (t < NCLS) lg[t] = red[t][0] + w2b[t];
    __syncthreads();
    if (t == 0){
        float m = -1e30f;
        for (int cc = 0; cc < NCLS; ++cc) m = fmaxf(m, lg[cc]);
        float se = 0.f;
        for (int cc = 0; cc < NCLS; ++cc) se += expf(lg[cc]-m);
        ml[0] = m; ml[1] = logf(se);
    }
    __syncthreads();
    if (t < NCLS) out[(size_t)node*NCLS + t] = lg[t] - ml[0] - ml[1];
}

extern "C" void kernel_launch(void* const* d_in, const int* in_sizes, int n_in,
                              void* d_out, int out_size, void* d_ws, size_t ws_size,
                              hipStream_t stream){
    const float* feat = (const float*)d_in[0];
    const float* z0i  = (const float*)d_in[1];
    const float* w1p  = (const float*)d_in[2];
    const float* EAp  = (const float*)d_in[3];
    const float* w2w  = (const float*)d_in[4];
    const float* w2b  = (const float*)d_in[5];
    const float* w22p = (const float*)d_in[7];
    const float* evp  = (const float*)d_in[8];
    const int* ei   = (const int*)d_in[9];
    const int* ej   = (const int*)d_in[10];
    float* out = (float*)d_out;

    // ---- diagnostic: verify input layout assumptions; on mismatch emit -100 signature ----
    const int NN = Nn*Nn;
    int ok = (n_in == 11) && (out_size == Nn*NCLS)
           && in_sizes[0]==NF && in_sizes[1]==NF && in_sizes[2]==NN && in_sizes[3]==NN
           && in_sizes[4]==2*Ff*NCLS && in_sizes[5]==NCLS && in_sizes[6]==NN && in_sizes[7]==NN
           && in_sizes[8]==Ne && in_sizes[9]==Ne && in_sizes[10]==Ne;
    if (!ok){
        k_fillc<<<(out_size+255)/256, 256, 0, stream>>>(out, -100.0f, out_size);
        return;
    }

    float *yA,*yB,*zA,*zB,*t1,*T1,*G,*col,*P,*cc,*hV; u32 *hK,*slot;
    hipGetSymbolAddress((void**)&yA,  HIP_SYMBOL(g_yA));
    hipGetSymbolAddress((void**)&yB,  HIP_SYMBOL(g_yB));
    hipGetSymbolAddress((void**)&zA,  HIP_SYMBOL(g_zA));
    hipGetSymbolAddress((void**)&zB,  HIP_SYMBOL(g_zB));
    hipGetSymbolAddress((void**)&t1,  HIP_SYMBOL(g_t1));
    hipGetSymbolAddress((void**)&T1,  HIP_SYMBOL(g_T1));
    hipGetSymbolAddress((void**)&G,   HIP_SYMBOL(g_G));
    hipGetSymbolAddress((void**)&col, HIP_SYMBOL(g_col));
    hipGetSymbolAddress((void**)&P,   HIP_SYMBOL(g_P));
    hipGetSymbolAddress((void**)&cc,  HIP_SYMBOL(g_cc));
    hipGetSymbolAddress((void**)&hV,  HIP_SYMBOL(g_hV));
    hipGetSymbolAddress((void**)&hK,  HIP_SYMBOL(g_hK));
    hipGetSymbolAddress((void**)&slot,HIP_SYMBOL(g_slot));

    dim3 gD(Ff/64, Nn/64);             // (4,64) for dense/yg kernels

    k_copy<<<NF/256, 256, 0, stream>>>(yA, feat, NF);
    k_copy<<<NF/256, 256, 0, stream>>>(zA, z0i, NF);
    k_copy<<<Ne/256, 256, 0, stream>>>(cc, evp, Ne);
    k_hkeys_clear<<<TSZ/256, 256, 0, stream>>>(hK);
    k_hsetup<<<Ne/256, 256, 0, stream>>>(hK, slot, ei, ej);

    float *y = yA, *yn = yB, *z = zA, *zn = zB;
    for (int t = 1; t <= 4; ++t){
        // --- temp assembly into t1 ---
        k_zero<<<Ff*Ff/256, 256, 0, stream>>>(G, Ff*Ff);
        k_gram<<<dim3(4,4,16), 256, 0, stream>>>(G, y, y);
        if (t == 1){
            k_zero<<<1, 256, 0, stream>>>(col, Ff);
            k_colsum<<<64, 256, 0, stream>>>(col, y);
            k_yg<1><<<gD, 256, 0, stream>>>(t1, y, G, col);       // t1 = colsum - y@(y^T y)
        } else {
            k_yg<0><<<gD, 256, 0, stream>>>(t1, y, G, T1);        // t1 = T1 - y@(y^T y)
        }
        k_dense<0><<<gD, 256, 0, stream>>>(t1, EAp, w22p, y, nullptr, nullptr);     // += mEA@y
        if (t >= 2)
            k_dense<1><<<gD, 256, 0, stream>>>(t1, EAp, w22p, y, nullptr, nullptr); // -= mEA^T@y
        k_sparseT<<<Ne/4, 256, 0, stream>>>(t1, y, cc, P, ei, ej, (t >= 2) ? 1 : 0);
        // --- y update ---
        k_dense<2><<<gD, 256, 0, stream>>>(yn, w1p, nullptr, t1, feat, nullptr);    // feat + 0.5*sigmoid(w1@t1)
        // --- z update ---
        k_dense<3><<<gD, 256, 0, stream>>>(zn, EAp, w22p, z, nullptr, z);           // z - mEA@z
        k_sparseZ<<<Ne/4, 256, 0, stream>>>(zn, z, cc, ei, ej);                     // -= sparse part
        // --- prepare next layer (EP/M/T1) ---
        if (t < 4){
            k_p<<<Ne/4, 256, 0, stream>>>(P, z, ei, ej, evp);
            k_zero<<<TSZ/256, 256, 0, stream>>>(hV, TSZ);
            k_hacc<<<Ne/256, 256, 0, stream>>>(hV, P, slot);
            k_ep<<<Ne/4, 256, 0, stream>>>(cc, y, ei, ej, evp, hV, slot);
            k_zero<<<Ff*Ff/256, 256, 0, stream>>>(G, Ff*Ff);
            k_gram<<<dim3(4,4,16), 256, 0, stream>>>(G, y, yn);                     // y^T @ y_next
            k_yg<2><<<gD, 256, 0, stream>>>(T1, y, G, nullptr);                     // T1 = y @ (y^T y_next)
        }
        float* tmp = y; y = yn; yn = tmp;
        tmp = z; z = zn; zn = tmp;
    }
    k_head<<<Nn, 256, 0, stream>>>(out, y, z, w2w, w2b);
}

// Round 5
// 2669.894 us; speedup vs baseline: 4.2004x; 4.2004x over previous
//
#include <hip/hip_runtime.h>

#define Nn 4096
#define Ff 256
#define NCLS 16
#define Ne 65536
#define TSZ 262144
#define NF (Nn*Ff)
#define NNx (Nn*Nn)

typedef unsigned short u16;
typedef unsigned int u32;
typedef __attribute__((ext_vector_type(8))) short short8;
typedef __attribute__((ext_vector_type(4))) float float4v;

__device__ __forceinline__ float bfh(u16 u){ return __uint_as_float(((u32)u)<<16); }
__device__ __forceinline__ u16 f2bf(float f){
    u32 u = __float_as_uint(f);
    return (u16)((u + 0x7FFFu + ((u>>16)&1u)) >> 16);
}
__device__ __forceinline__ void gload16(const u16* g, u16* l){
    __builtin_amdgcn_global_load_lds(
        (const __attribute__((address_space(1))) u32*)(const void*)g,
        (__attribute__((address_space(3))) u32*)(void*)l, 16, 0, 0);
}

// ---------------- device-global workspace ----------------
__device__ float g_yA[NF], g_yB[NF], g_zA[NF], g_zB[NF], g_t1[NF], g_T1[NF];
__device__ float g_G[Ff*Ff], g_col[Ff], g_P[Ne], g_cc[Ne], g_hV[TSZ];
__device__ u32 g_hK[TSZ], g_slot[Ne];
__device__ __align__(16) u16 g_w1h[NNx], g_w1l[NNx];
__device__ __align__(16) u16 g_meh[NNx], g_mel[NNx];
__device__ __align__(16) u16 g_mth[NNx], g_mtl[NNx];
__device__ __align__(16) u16 g_xh[NF],  g_xl[NF];    // X^T split [256][4096]
__device__ __align__(16) u16 g_x2h[NF], g_x2l[NF];   // X^T split (second)
__device__ __align__(16) u16 g_yh[NF],  g_yl[NF];    // y row-major split [4096][256]
__device__ __align__(16) u16 g_gth[Ff*Ff], g_gtl[Ff*Ff]; // G^T split [256][256]

// ---------------- utility ----------------
__global__ __launch_bounds__(256) void k_copy(float* dst, const float* src, int n){
    int i = blockIdx.x*256 + threadIdx.x;
    if (i < n) dst[i] = src[i];
}
__global__ __launch_bounds__(256) void k_zero(float* p, int n){
    int i = blockIdx.x*256 + threadIdx.x;
    if (i < n) p[i] = 0.f;
}
__global__ __launch_bounds__(256) void k_fillc(float* p, float v, int n){
    int i = blockIdx.x*256 + threadIdx.x;
    if (i < n) p[i] = v;
}
__global__ __launch_bounds__(256) void k_hkeys_clear(u32* K){
    int i = blockIdx.x*256 + threadIdx.x;
    if (i < TSZ) K[i] = 0xFFFFFFFFu;
}
__global__ __launch_bounds__(256) void k_hsetup(u32* K, u32* slot, const int* ei, const int* ej){
    int e = blockIdx.x*256 + threadIdx.x;
    if (e >= Ne) return;
    u32 key = ((u32)ei[e] << 12) | (u32)ej[e];
    u32 h = (key * 2654435761u) & (TSZ-1);
    for (;;){
        u32 old = atomicCAS(&K[h], 0xFFFFFFFFu, key);
        if (old == 0xFFFFFFFFu || old == key){ slot[e] = h; break; }
        h = (h+1) & (TSZ-1);
    }
}
__global__ __launch_bounds__(256) void k_hacc(float* V, const float* P, const u32* slot){
    int e = blockIdx.x*256 + threadIdx.x;
    if (e < Ne) atomicAdd(&V[slot[e]], P[e]);
}

// ---------------- split precompute kernels ----------------
__global__ __launch_bounds__(256) void k_split(u16* hi, u16* lo, const float* w){
    int i = blockIdx.x*256 + threadIdx.x;
    float v = w[i];
    u16 h = f2bf(v); hi[i] = h; lo[i] = f2bf(v - bfh(h));
}
__global__ __launch_bounds__(256) void k_splitME(u16* hi, u16* lo, const float* ea, const float* w22){
    int i = blockIdx.x*256 + threadIdx.x;
    float v = 0.5f*ea[i]*w22[i];
    u16 h = f2bf(v); hi[i] = h; lo[i] = f2bf(v - bfh(h));
}
// transposed split of mEA: out[(c0+r)*Nn + r0+c] = in[(r0+c)*Nn + c0+r]
__global__ __launch_bounds__(256) void k_splitMET(u16* hi, u16* lo, const float* ea, const float* w22){
    __shared__ float T[64][65];
    int r0 = blockIdx.y*64, c0 = blockIdx.x*64;
    int c = threadIdx.x & 63, rr = threadIdx.x >> 6;
    for (int q = 0; q < 16; ++q){
        int r = q*4 + rr;
        size_t idx = (size_t)(r0+r)*Nn + c0 + c;
        T[r][c] = 0.5f*ea[idx]*w22[idx];
    }
    __syncthreads();
    for (int q = 0; q < 16; ++q){
        int r = q*4 + rr;
        float v = T[c][r];
        size_t o = (size_t)(c0+r)*Nn + r0 + c;
        u16 h = f2bf(v); hi[o] = h; lo[o] = f2bf(v - bfh(h));
    }
}
// X [4096][256] f32 -> X^T split [256][4096] u16 hi/lo
__global__ __launch_bounds__(256) void k_splitXT(u16* hi, u16* lo, const float* X){
    __shared__ float T[64][65];
    int r0 = blockIdx.y*64, c0 = blockIdx.x*64;   // r0 over 4096, c0 over 256
    int c = threadIdx.x & 63, rr = threadIdx.x >> 6;
    for (int q = 0; q < 16; ++q){
        int r = q*4 + rr;
        T[r][c] = X[(size_t)(r0+r)*Ff + c0 + c];
    }
    __syncthreads();
    for (int q = 0; q < 16; ++q){
        int r = q*4 + rr;
        float v = T[c][r];
        size_t o = (size_t)(c0+r)*Nn + r0 + c;
        u16 h = f2bf(v); hi[o] = h; lo[o] = f2bf(v - bfh(h));
    }
}
// G [256][256] f32 -> G^T split [256][256]
__global__ __launch_bounds__(256) void k_splitGT(u16* hi, u16* lo, const float* Gm){
    __shared__ float T[64][65];
    int r0 = blockIdx.y*64, c0 = blockIdx.x*64;
    int c = threadIdx.x & 63, rr = threadIdx.x >> 6;
    for (int q = 0; q < 16; ++q){
        int r = q*4 + rr;
        T[r][c] = Gm[(r0+r)*Ff + c0 + c];
    }
    __syncthreads();
    for (int q = 0; q < 16; ++q){
        int r = q*4 + rr;
        float v = T[c][r];
        int o = (c0+r)*Ff + r0 + c;
        u16 h = f2bf(v); hi[o] = h; lo[o] = f2bf(v - bfh(h));
    }
}

// ---------------- shared MFMA tile core ----------------
// A-operand arrays: [rows][K] (rows = output rows), B-operand arrays: [cols][K].
// Stages a 64(row)x64(k) tile of each into LDS via global_load_lds with XOR
// chunk-swizzle applied on the global source; reads back with swizzled ds_read_b128.
__device__ __forceinline__ void mm_tile(
    const u16* __restrict__ Ahp, const u16* __restrict__ Alp,
    const u16* __restrict__ Bhp, const u16* __restrict__ Blp,
    size_t sA, size_t sB, int i0, int j0, int k0,
    u16* LAh, u16* LAl, u16* LBh, u16* LBl,
    float4v* acc, int lane, int w)
{
    const int g1 = w*64 + lane;
    const int g2 = g1 + 256;
    const int r1 = g1>>3, p1 = g1&7, r2 = g2>>3, p2 = g2&7;
    const size_t a1 = (size_t)(i0+r1)*sA + (size_t)(k0 + ((p1 ^ (r1&7))<<3));
    const size_t a2 = (size_t)(i0+r2)*sA + (size_t)(k0 + ((p2 ^ (r2&7))<<3));
    const size_t b1 = (size_t)(j0+r1)*sB + (size_t)(k0 + ((p1 ^ (r1&7))<<3));
    const size_t b2 = (size_t)(j0+r2)*sB + (size_t)(k0 + ((p2 ^ (r2&7))<<3));
    __syncthreads();                       // LDS safe to overwrite
    gload16(Ahp + a1, LAh + g1*8);
    gload16(Ahp + a2, LAh + g2*8);
    gload16(Alp + a1, LAl + g1*8);
    gload16(Alp + a2, LAl + g2*8);
    gload16(Bhp + b1, LBh + g1*8);
    gload16(Bhp + b2, LBh + g2*8);
    gload16(Blp + b1, LBl + g1*8);
    gload16(Blp + b2, LBl + g2*8);
    __syncthreads();                       // compiler drains vmcnt before barrier
    const int arow = w*16 + (lane&15);
    const int aswz = arow & 7;
    #pragma unroll
    for (int kk = 0; kk < 2; ++kk){
        const int ch = kk*4 + (lane>>4);
        short8 ah = *(const short8*)(LAh + arow*64 + ((ch ^ aswz)<<3));
        short8 al = *(const short8*)(LAl + arow*64 + ((ch ^ aswz)<<3));
        #pragma unroll
        for (int c = 0; c < 4; ++c){
            const int brow = c*16 + (lane&15);
            const int bo = brow*64 + ((ch ^ (brow&7))<<3);
            short8 bh = *(const short8*)(LBh + bo);
            short8 bl = *(const short8*)(LBl + bo);
            acc[c] = __builtin_amdgcn_mfma_f32_16x16x32_bf16(ah, bh, acc[c], 0,0,0);
            acc[c] = __builtin_amdgcn_mfma_f32_16x16x32_bf16(ah, bl, acc[c], 0,0,0);
            acc[c] = __builtin_amdgcn_mfma_f32_16x16x32_bf16(al, bh, acc[c], 0,0,0);
        }
    }
}

// ---------------- generic GEMM: out[4096 or Nn rows][256] ----------------
// V 0: out += acc     V 1: out -= acc    V 2: out = aux1 + 0.5*sigmoid(acc)
// V 3: out = aux1[idx] - acc             V 4: out = aux1[col] - acc
// V 5: out = acc
template<int V>
__global__ __launch_bounds__(256) void k_mm(float* __restrict__ out,
        const u16* __restrict__ Ahp, const u16* __restrict__ Alp,
        const u16* __restrict__ Bhp, const u16* __restrict__ Blp,
        size_t sA, size_t sB, int nkt,
        const float* __restrict__ aux1){
    __shared__ u16 LAh[4096], LAl[4096], LBh[4096], LBl[4096];
    const int tid = threadIdx.x, lane = tid & 63, w = tid >> 6;
    const int j0 = blockIdx.x*64, i0 = blockIdx.y*64;
    float4v acc[4];
    #pragma unroll
    for (int c = 0; c < 4; ++c) acc[c] = (float4v){0.f,0.f,0.f,0.f};
    for (int kt = 0; kt < nkt; ++kt)
        mm_tile(Ahp, Alp, Bhp, Blp, sA, sB, i0, j0, kt*64, LAh, LAl, LBh, LBl, acc, lane, w);
    #pragma unroll
    for (int c = 0; c < 4; ++c)
        #pragma unroll
        for (int r = 0; r < 4; ++r){
            int grow = i0 + w*16 + (lane>>4)*4 + r;
            int gcol = j0 + c*16 + (lane&15);
            size_t idx = (size_t)grow*Ff + gcol;
            float v = acc[c][r];
            if constexpr (V == 0) out[idx] += v;
            if constexpr (V == 1) out[idx] -= v;
            if constexpr (V == 2) out[idx] = aux1[idx] + 0.5f*(1.f/(1.f+expf(-v)));
            if constexpr (V == 3) out[idx] = aux1[idx] - v;
            if constexpr (V == 4) out[idx] = aux1[gcol] - v;
            if constexpr (V == 5) out[idx] = v;
        }
}

// ---------------- Gram GEMM: G[256][256] += A^T-ish, K split over blockIdx.z ----------------
__global__ __launch_bounds__(256) void k_gram_mm(float* __restrict__ G,
        const u16* __restrict__ Ahp, const u16* __restrict__ Alp,
        const u16* __restrict__ Bhp, const u16* __restrict__ Blp){
    __shared__ u16 LAh[4096], LAl[4096], LBh[4096], LBl[4096];
    const int tid = threadIdx.x, lane = tid & 63, w = tid >> 6;
    const int j0 = blockIdx.x*64, i0 = blockIdx.y*64, kb = blockIdx.z*256;
    float4v acc[4];
    #pragma unroll
    for (int c = 0; c < 4; ++c) acc[c] = (float4v){0.f,0.f,0.f,0.f};
    for (int kt = 0; kt < 4; ++kt)
        mm_tile(Ahp, Alp, Bhp, Blp, (size_t)Nn, (size_t)Nn, i0, j0, kb + kt*64, LAh, LAl, LBh, LBl, acc, lane, w);
    #pragma unroll
    for (int c = 0; c < 4; ++c)
        #pragma unroll
        for (int r = 0; r < 4; ++r){
            int grow = i0 + w*16 + (lane>>4)*4 + r;
            int gcol = j0 + c*16 + (lane&15);
            atomicAdd(&G[grow*Ff + gcol], acc[c][r]);
        }
}

__global__ __launch_bounds__(256) void k_colsum(float* col, const float* __restrict__ y){
    int j = threadIdx.x;
    int r0 = blockIdx.x*64;
    float s = 0.f;
    for (int i = 0; i < 64; ++i) s += y[(size_t)(r0+i)*Ff + j];
    atomicAdd(&col[j], s);
}

// ---------------- sparse scatters ----------------
__global__ __launch_bounds__(256) void k_sparseT(float* __restrict__ t1, const float* __restrict__ y,
        const float* __restrict__ c, const float* __restrict__ P,
        const int* __restrict__ ei, const int* __restrict__ ej, int useM){
    int e = blockIdx.x*4 + (threadIdx.x >> 6);
    int lane = threadIdx.x & 63;
    int i = ei[e], j = ej[e];
    float ce = c[e];
    #pragma unroll
    for (int q = 0; q < 4; ++q){
        int f = lane + q*64;
        atomicAdd(&t1[(size_t)i*Ff + f], ce * y[(size_t)j*Ff + f]);
    }
    if (useM){
        float pe = -0.5f * P[e];
        #pragma unroll
        for (int q = 0; q < 4; ++q){
            int f = lane + q*64;
            atomicAdd(&t1[(size_t)j*Ff + f], pe * y[(size_t)i*Ff + f]);
        }
    }
}
__global__ __launch_bounds__(256) void k_sparseZ(float* __restrict__ zn, const float* __restrict__ z,
        const float* __restrict__ c, const int* __restrict__ ei, const int* __restrict__ ej){
    int e = blockIdx.x*4 + (threadIdx.x >> 6);
    int lane = threadIdx.x & 63;
    int i = ei[e], j = ej[e];
    float ce = c[e];
    #pragma unroll
    for (int q = 0; q < 4; ++q){
        int f = lane + q*64;
        atomicAdd(&zn[(size_t)i*Ff + f], -ce * z[(size_t)j*Ff + f]);
    }
}
__global__ __launch_bounds__(256) void k_p(float* __restrict__ P, const float* __restrict__ z,
        const int* __restrict__ ei, const int* __restrict__ ej, const float* __restrict__ ev){
    int e = blockIdx.x*4 + (threadIdx.x >> 6);
    int lane = threadIdx.x & 63;
    int i = ei[e], j = ej[e];
    float s = 0.f;
    #pragma unroll
    for (int q = 0; q < 4; ++q){
        int f = lane + q*64;
        float d = z[(size_t)i*Ff + f] - z[(size_t)j*Ff + f];
        s += d*d;
    }
    #pragma unroll
    for (int o = 32; o; o >>= 1) s += __shfl_xor(s, o);
    if (lane == 0) P[e] = sqrtf(s) * ev[e];
}
__global__ __launch_bounds__(256) void k_ep(float* __restrict__ c, const float* __restrict__ y,
        const int* __restrict__ ei, const int* __restrict__ ej, const float* __restrict__ ev,
        const float* __restrict__ V, const u32* __restrict__ slot){
    int e = blockIdx.x*4 + (threadIdx.x >> 6);
    int lane = threadIdx.x & 63;
    int i = ei[e], j = ej[e];
    float s = 0.f;
    #pragma unroll
    for (int q = 0; q < 4; ++q){
        int f = lane + q*64;
        s += y[(size_t)i*Ff + f] * y[(size_t)j*Ff + f];
    }
    #pragma unroll
    for (int o = 32; o; o >>= 1) s += __shfl_xor(s, o);
    if (lane == 0) c[e] = ev[e] * (s - 0.5f * V[slot[e]]);
}

// ---------------- head ----------------
__global__ __launch_bounds__(256) void k_head(float* __restrict__ out, const float* __restrict__ y,
                                              const float* __restrict__ z, const float* __restrict__ w2w,
                                              const float* __restrict__ w2b){
    const int node = blockIdx.x, t = threadIdx.x;
    float yv = y[(size_t)node*Ff + t], zv = z[(size_t)node*Ff + t];
    float yc = fminf(fmaxf(yv, -1e37f), 1e37f);
    float zc = fminf(fmaxf(zv, -1e37f), 1e37f);
    __shared__ float sy[256], sz[256];
    sy[t] = fabsf(yc); sz[t] = fabsf(zc);
    __syncthreads();
    for (int s = 128; s; s >>= 1){ if (t < s){ sy[t]=fmaxf(sy[t],sy[t+s]); sz[t]=fmaxf(sz[t],sz[t+s]); } __syncthreads(); }
    float my_ = fmaxf(sy[0], 1e-30f), mz_ = fmaxf(sz[0], 1e-30f);
    __syncthreads();
    float ysc = yc/my_, zsc = zc/mz_;
    sy[t] = ysc*ysc; sz[t] = zsc*zsc;
    __syncthreads();
    for (int s = 128; s; s >>= 1){ if (t < s){ sy[t]+=sy[t+s]; sz[t]+=sz[t+s]; } __syncthreads(); }
    float ny = fmaxf(my_*sqrtf(sy[0]), 1e-12f);
    float nz = fmaxf(mz_*sqrtf(sz[0]), 1e-12f);
    float ynv = yc/ny, znv = zc/nz;
    float acc[NCLS];
    #pragma unroll
    for (int cc = 0; cc < NCLS; ++cc)
        acc[cc] = znv*w2w[t*NCLS+cc] + ynv*w2w[(Ff+t)*NCLS+cc];
    __shared__ float red[NCLS][257];
    #pragma unroll
    for (int cc = 0; cc < NCLS; ++cc) red[cc][t] = acc[cc];
    __syncthreads();
    for (int s = 128; s; s >>= 1){
        if (t < s){
            #pragma unroll
            for (int cc = 0; cc < NCLS; ++cc) red[cc][t] += red[cc][t+s];
        }
        __syncthreads();
    }
    __shared__ float lg[NCLS];
    __shared__ float ml[2];
    if (t < NCLS) lg[t] = red[t][0] + w2b[t];
    __syncthreads();
    if (t == 0){
        float m = -1e30f;
        for (int cc = 0; cc < NCLS; ++cc) m = fmaxf(m, lg[cc]);
        float se = 0.f;
        for (int cc = 0; cc < NCLS; ++cc) se += expf(lg[cc]-m);
        ml[0] = m; ml[1] = logf(se);
    }
    __syncthreads();
    if (t < NCLS) out[(size_t)node*NCLS + t] = lg[t] - ml[0] - ml[1];
}

extern "C" void kernel_launch(void* const* d_in, const int* in_sizes, int n_in,
                              void* d_out, int out_size, void* d_ws, size_t ws_size,
                              hipStream_t stream){
    const float* feat = (const float*)d_in[0];
    const float* z0i  = (const float*)d_in[1];
    const float* w1p  = (const float*)d_in[2];
    const float* EAp  = (const float*)d_in[3];
    const float* w2w  = (const float*)d_in[4];
    const float* w2b  = (const float*)d_in[5];
    const float* w22p = (const float*)d_in[7];
    const float* evp  = (const float*)d_in[8];
    const int* ei   = (const int*)d_in[9];
    const int* ej   = (const int*)d_in[10];
    float* out = (float*)d_out;

    int ok = (n_in == 11) && (out_size == Nn*NCLS)
           && in_sizes[0]==NF && in_sizes[1]==NF && in_sizes[2]==NNx && in_sizes[3]==NNx
           && in_sizes[4]==2*Ff*NCLS && in_sizes[5]==NCLS && in_sizes[6]==NNx && in_sizes[7]==NNx
           && in_sizes[8]==Ne && in_sizes[9]==Ne && in_sizes[10]==Ne;
    if (!ok){
        k_fillc<<<(out_size+255)/256, 256, 0, stream>>>(out, -100.0f, out_size);
        return;
    }

    float *yA,*yB,*zA,*zB,*t1,*T1,*G,*col,*P,*cc,*hV; u32 *hK,*slot;
    u16 *w1h,*w1l,*meh,*mel,*mth,*mtl,*xh,*xl,*x2h,*x2l,*yh,*yl,*gth,*gtl;
    hipGetSymbolAddress((void**)&yA,  HIP_SYMBOL(g_yA));
    hipGetSymbolAddress((void**)&yB,  HIP_SYMBOL(g_yB));
    hipGetSymbolAddress((void**)&zA,  HIP_SYMBOL(g_zA));
    hipGetSymbolAddress((void**)&zB,  HIP_SYMBOL(g_zB));
    hipGetSymbolAddress((void**)&t1,  HIP_SYMBOL(g_t1));
    hipGetSymbolAddress((void**)&T1,  HIP_SYMBOL(g_T1));
    hipGetSymbolAddress((void**)&G,   HIP_SYMBOL(g_G));
    hipGetSymbolAddress((void**)&col, HIP_SYMBOL(g_col));
    hipGetSymbolAddress((void**)&P,   HIP_SYMBOL(g_P));
    hipGetSymbolAddress((void**)&cc,  HIP_SYMBOL(g_cc));
    hipGetSymbolAddress((void**)&hV,  HIP_SYMBOL(g_hV));
    hipGetSymbolAddress((void**)&hK,  HIP_SYMBOL(g_hK));
    hipGetSymbolAddress((void**)&slot,HIP_SYMBOL(g_slot));
    hipGetSymbolAddress((void**)&w1h, HIP_SYMBOL(g_w1h));
    hipGetSymbolAddress((void**)&w1l, HIP_SYMBOL(g_w1l));
    hipGetSymbolAddress((void**)&meh, HIP_SYMBOL(g_meh));
    hipGetSymbolAddress((void**)&mel, HIP_SYMBOL(g_mel));
    hipGetSymbolAddress((void**)&mth, HIP_SYMBOL(g_mth));
    hipGetSymbolAddress((void**)&mtl, HIP_SYMBOL(g_mtl));
    hipGetSymbolAddress((void**)&xh,  HIP_SYMBOL(g_xh));
    hipGetSymbolAddress((void**)&xl,  HIP_SYMBOL(g_xl));
    hipGetSymbolAddress((void**)&x2h, HIP_SYMBOL(g_x2h));
    hipGetSymbolAddress((void**)&x2l, HIP_SYMBOL(g_x2l));
    hipGetSymbolAddress((void**)&yh,  HIP_SYMBOL(g_yh));
    hipGetSymbolAddress((void**)&yl,  HIP_SYMBOL(g_yl));
    hipGetSymbolAddress((void**)&gth, HIP_SYMBOL(g_gth));
    hipGetSymbolAddress((void**)&gtl, HIP_SYMBOL(g_gtl));

    const dim3 gG(Ff/64, Nn/64);       // (4,64) 256 blocks
    const dim3 gXT(Ff/64, Nn/64);      // transpose grids
    const dim3 gMET(Nn/64, Nn/64);
    const dim3 gGT(Ff/64, Ff/64);
    const dim3 gGram(4, 4, 16);

    // ---- constant-matrix splits (per launch; deterministic) ----
    k_split  <<<NNx/256, 256, 0, stream>>>(w1h, w1l, w1p);
    k_splitME<<<NNx/256, 256, 0, stream>>>(meh, mel, EAp, w22p);
    k_splitMET<<<gMET, 256, 0, stream>>>(mth, mtl, EAp, w22p);

    k_copy<<<NF/256, 256, 0, stream>>>(yA, feat, NF);
    k_copy<<<NF/256, 256, 0, stream>>>(zA, z0i, NF);
    k_copy<<<Ne/256, 256, 0, stream>>>(cc, evp, Ne);
    k_hkeys_clear<<<TSZ/256, 256, 0, stream>>>(hK);
    k_hsetup<<<Ne/256, 256, 0, stream>>>(hK, slot, ei, ej);

    float *y = yA, *yn = yB, *z = zA, *zn = zB;
    for (int t = 1; t <= 4; ++t){
        // splits of current y
        k_splitXT<<<gXT, 256, 0, stream>>>(xh, xl, y);          // y^T
        k_split  <<<NF/256, 256, 0, stream>>>(yh, yl, y);       // y row-major
        // G = y^T y
        k_zero<<<Ff*Ff/256, 256, 0, stream>>>(G, Ff*Ff);
        k_gram_mm<<<gGram, 256, 0, stream>>>(G, xh, xl, xh, xl);
        k_splitGT<<<gGT, 256, 0, stream>>>(gth, gtl, G);
        // t1 = (T1 | colsum) - y@G
        if (t == 1){
            k_zero<<<1, 256, 0, stream>>>(col, Ff);
            k_colsum<<<64, 256, 0, stream>>>(col, y);
            k_mm<4><<<gG, 256, 0, stream>>>(t1, yh, yl, gth, gtl, (size_t)Ff, (size_t)Ff, 4, col);
        } else {
            k_mm<3><<<gG, 256, 0, stream>>>(t1, yh, yl, gth, gtl, (size_t)Ff, (size_t)Ff, 4, T1);
        }
        // t1 += mEA@y ; t1 -= mEA^T@y (t>=2)
        k_mm<0><<<gG, 256, 0, stream>>>(t1, meh, mel, xh, xl, (size_t)Nn, (size_t)Nn, 64, nullptr);
        if (t >= 2)
            k_mm<1><<<gG, 256, 0, stream>>>(t1, mth, mtl, xh, xl, (size_t)Nn, (size_t)Nn, 64, nullptr);
        k_sparseT<<<Ne/4, 256, 0, stream>>>(t1, y, cc, P, ei, ej, (t >= 2) ? 1 : 0);
        // yn = feat + 0.5*sigmoid(w1@t1)
        k_splitXT<<<gXT, 256, 0, stream>>>(x2h, x2l, t1);
        k_mm<2><<<gG, 256, 0, stream>>>(yn, w1h, w1l, x2h, x2l, (size_t)Nn, (size_t)Nn, 64, feat);
        // zn = z - mEA@z - sparse
        k_splitXT<<<gXT, 256, 0, stream>>>(x2h, x2l, z);
        k_mm<3><<<gG, 256, 0, stream>>>(zn, meh, mel, x2h, x2l, (size_t)Nn, (size_t)Nn, 64, z);
        k_sparseZ<<<Ne/4, 256, 0, stream>>>(zn, z, cc, ei, ej);
        // next-layer EP coefficients and T1 carry
        if (t < 4){
            k_p<<<Ne/4, 256, 0, stream>>>(P, z, ei, ej, evp);
            k_zero<<<TSZ/256, 256, 0, stream>>>(hV, TSZ);
            k_hacc<<<Ne/256, 256, 0, stream>>>(hV, P, slot);
            k_ep<<<Ne/4, 256, 0, stream>>>(cc, y, ei, ej, evp, hV, slot);
            k_splitXT<<<gXT, 256, 0, stream>>>(x2h, x2l, yn);   // yn^T
            k_zero<<<Ff*Ff/256, 256, 0, stream>>>(G, Ff*Ff);
            k_gram_mm<<<gGram, 256, 0, stream>>>(G, xh, xl, x2h, x2l);   // y^T yn
            k_splitGT<<<gGT, 256, 0, stream>>>(gth, gtl, G);
            k_mm<5><<<gG, 256, 0, stream>>>(T1, yh, yl, gth, gtl, (size_t)Ff, (size_t)Ff, 4, nullptr);
        }
        float* tmp = y; y = yn; yn = tmp;
        tmp = z; z = zn; zn = tmp;
    }
    k_head<<<Nn, 256, 0, stream>>>(out, y, z, w2w, w2b);
}

// Round 6
// 1367.939 us; speedup vs baseline: 8.1982x; 1.9518x over previous
//
#include <hip/hip_runtime.h>

#define Nn 4096
#define Ff 256
#define NCLS 16
#define Ne 65536
#define TSZ 262144
#define NF (Nn*Ff)
#define NNx (Nn*Nn)
#define KS 8

typedef unsigned short u16;
typedef unsigned int u32;
typedef __attribute__((ext_vector_type(8))) short short8;
typedef __attribute__((ext_vector_type(4))) float float4v;

__device__ __forceinline__ float bfh(u16 u){ return __uint_as_float(((u32)u)<<16); }
__device__ __forceinline__ u16 f2bf(float f){
    u32 u = __float_as_uint(f);
    return (u16)((u + 0x7FFFu + ((u>>16)&1u)) >> 16);
}
__device__ __forceinline__ void gload16(const u16* g, u16* l){
    __builtin_amdgcn_global_load_lds(
        (const __attribute__((address_space(1))) u32*)(const void*)g,
        (__attribute__((address_space(3))) u32*)(void*)l, 16, 0, 0);
}

// ---------------- device-global workspace ----------------
__device__ float g_yA[NF], g_yB[NF], g_zA[NF], g_zB[NF], g_t1[NF], g_T1[NF];
__device__ float g_G[Ff*Ff], g_col[Ff], g_P[Ne], g_cc[Ne], g_hV[TSZ];
__device__ float g_pb[(size_t)KS*NF];
__device__ u32 g_hK[TSZ], g_slot[Ne];
__device__ int g_cntI[Nn], g_cntJ[Nn], g_rpI[Nn+1], g_rpJ[Nn+1], g_fI[Nn], g_fJ[Nn];
__device__ int g_lI[Ne], g_lJ[Ne];
__device__ __align__(16) u16 g_w1h[NNx], g_w1l[NNx];
__device__ __align__(16) u16 g_meh[NNx], g_mel[NNx];
__device__ __align__(16) u16 g_mth[NNx], g_mtl[NNx];
__device__ __align__(16) u16 g_xAh[NF], g_xAl[NF];   // y^T split (current)
__device__ __align__(16) u16 g_xBh[NF], g_xBl[NF];   // y^T split (next)
__device__ __align__(16) u16 g_x2h[NF], g_x2l[NF];   // t1^T / z^T scratch split
__device__ __align__(16) u16 g_yhA[NF], g_ylA[NF];   // y row split (current)
__device__ __align__(16) u16 g_yhB[NF], g_ylB[NF];   // y row split (next)
__device__ __align__(16) u16 g_gth[Ff*Ff], g_gtl[Ff*Ff];

// ---------------- utility ----------------
__global__ __launch_bounds__(256) void k_copy(float* dst, const float* src, int n){
    int i = blockIdx.x*256 + threadIdx.x;
    if (i < n) dst[i] = src[i];
}
__global__ __launch_bounds__(256) void k_zero(float* p, int n){
    int i = blockIdx.x*256 + threadIdx.x;
    if (i < n) p[i] = 0.f;
}
__global__ __launch_bounds__(256) void k_zeroi(int* p, int n){
    int i = blockIdx.x*256 + threadIdx.x;
    if (i < n) p[i] = 0;
}
__global__ __launch_bounds__(256) void k_fillc(float* p, float v, int n){
    int i = blockIdx.x*256 + threadIdx.x;
    if (i < n) p[i] = v;
}
__global__ __launch_bounds__(256) void k_hkeys_clear(u32* K){
    int i = blockIdx.x*256 + threadIdx.x;
    if (i < TSZ) K[i] = 0xFFFFFFFFu;
}
__global__ __launch_bounds__(256) void k_hsetup(u32* K, u32* slot, const int* ei, const int* ej){
    int e = blockIdx.x*256 + threadIdx.x;
    if (e >= Ne) return;
    u32 key = ((u32)ei[e] << 12) | (u32)ej[e];
    u32 h = (key * 2654435761u) & (TSZ-1);
    for (;;){
        u32 old = atomicCAS(&K[h], 0xFFFFFFFFu, key);
        if (old == 0xFFFFFFFFu || old == key){ slot[e] = h; break; }
        h = (h+1) & (TSZ-1);
    }
}
__global__ __launch_bounds__(256) void k_hacc(float* V, const float* P, const u32* slot){
    int e = blockIdx.x*256 + threadIdx.x;
    if (e < Ne) atomicAdd(&V[slot[e]], P[e]);
}

// ---------------- CSR build ----------------
__global__ __launch_bounds__(256) void k_count(int* cntI, int* cntJ, const int* ei, const int* ej){
    int e = blockIdx.x*256 + threadIdx.x;
    if (e < Ne){ atomicAdd(&cntI[ei[e]], 1); atomicAdd(&cntJ[ej[e]], 1); }
}
__global__ __launch_bounds__(1024) void k_scan(const int* cnt, int* rp){
    __shared__ int s[1024];
    int t = threadIdx.x, b = t*4;
    int a0 = cnt[b], a1 = cnt[b+1], a2 = cnt[b+2], a3 = cnt[b+3];
    int sum = a0+a1+a2+a3;
    s[t] = sum; __syncthreads();
    for (int o = 1; o < 1024; o <<= 1){
        int v = (t >= o) ? s[t-o] : 0;
        __syncthreads();
        s[t] += v;
        __syncthreads();
    }
    int excl = s[t] - sum;
    rp[b] = excl; rp[b+1] = excl+a0; rp[b+2] = excl+a0+a1; rp[b+3] = excl+a0+a1+a2;
    if (t == 1023) rp[4096] = s[1023];
}
__global__ __launch_bounds__(256) void k_fillcsr(const int* rpI, const int* rpJ, int* fI, int* fJ,
                                                 int* lI, int* lJ, const int* ei, const int* ej){
    int e = blockIdx.x*256 + threadIdx.x;
    if (e >= Ne) return;
    int i = ei[e], j = ej[e];
    lI[rpI[i] + atomicAdd(&fI[i], 1)] = e;
    lJ[rpJ[j] + atomicAdd(&fJ[j], 1)] = e;
}

// ---------------- split precompute ----------------
__global__ __launch_bounds__(256) void k_split(u16* hi, u16* lo, const float* w){
    int i = blockIdx.x*256 + threadIdx.x;
    float v = w[i];
    u16 h = f2bf(v); hi[i] = h; lo[i] = f2bf(v - bfh(h));
}
// fused mEA (row-major) + mEA^T split: one read pass over EA,w22
__global__ __launch_bounds__(256) void k_splitME2(u16* meh, u16* mel, u16* mth, u16* mtl,
                                                  const float* ea, const float* w22){
    __shared__ float T[64][65];
    int r0 = blockIdx.y*64, c0 = blockIdx.x*64;
    int c = threadIdx.x & 63, rr = threadIdx.x >> 6;
    for (int q = 0; q < 16; ++q){
        int r = q*4 + rr;
        size_t idx = (size_t)(r0+r)*Nn + c0 + c;
        float v = 0.5f*ea[idx]*w22[idx];
        T[r][c] = v;
        u16 h = f2bf(v); meh[idx] = h; mel[idx] = f2bf(v - bfh(h));
    }
    __syncthreads();
    for (int q = 0; q < 16; ++q){
        int r = q*4 + rr;
        float v = T[c][r];
        size_t o = (size_t)(c0+r)*Nn + r0 + c;
        u16 h = f2bf(v); mth[o] = h; mtl[o] = f2bf(v - bfh(h));
    }
}
// X [4096][256] f32 -> X^T split [256][4096]
__global__ __launch_bounds__(256) void k_splitXT(u16* hi, u16* lo, const float* X){
    __shared__ float T[64][65];
    int r0 = blockIdx.y*64, c0 = blockIdx.x*64;
    int c = threadIdx.x & 63, rr = threadIdx.x >> 6;
    for (int q = 0; q < 16; ++q){
        int r = q*4 + rr;
        T[r][c] = X[(size_t)(r0+r)*Ff + c0 + c];
    }
    __syncthreads();
    for (int q = 0; q < 16; ++q){
        int r = q*4 + rr;
        float v = T[c][r];
        size_t o = (size_t)(c0+r)*Nn + r0 + c;
        u16 h = f2bf(v); hi[o] = h; lo[o] = f2bf(v - bfh(h));
    }
}
__global__ __launch_bounds__(256) void k_splitGT(u16* hi, u16* lo, const float* Gm){
    __shared__ float T[64][65];
    int r0 = blockIdx.y*64, c0 = blockIdx.x*64;
    int c = threadIdx.x & 63, rr = threadIdx.x >> 6;
    for (int q = 0; q < 16; ++q){
        int r = q*4 + rr;
        T[r][c] = Gm[(r0+r)*Ff + c0 + c];
    }
    __syncthreads();
    for (int q = 0; q < 16; ++q){
        int r = q*4 + rr;
        float v = T[c][r];
        int o = (c0+r)*Ff + r0 + c;
        u16 h = f2bf(v); hi[o] = h; lo[o] = f2bf(v - bfh(h));
    }
}

// ---------------- small-GEMM MFMA tile core (64x64 tile, verified r5) ----------------
__device__ __forceinline__ void mm_tile(
    const u16* __restrict__ Ahp, const u16* __restrict__ Alp,
    const u16* __restrict__ Bhp, const u16* __restrict__ Blp,
    size_t sA, size_t sB, int i0, int j0, int k0,
    u16* LAh, u16* LAl, u16* LBh, u16* LBl,
    float4v* acc, int lane, int w)
{
    const int g1 = w*64 + lane;
    const int g2 = g1 + 256;
    const int r1 = g1>>3, p1 = g1&7, r2 = g2>>3, p2 = g2&7;
    const size_t a1 = (size_t)(i0+r1)*sA + (size_t)(k0 + ((p1 ^ (r1&7))<<3));
    const size_t a2 = (size_t)(i0+r2)*sA + (size_t)(k0 + ((p2 ^ (r2&7))<<3));
    const size_t b1 = (size_t)(j0+r1)*sB + (size_t)(k0 + ((p1 ^ (r1&7))<<3));
    const size_t b2 = (size_t)(j0+r2)*sB + (size_t)(k0 + ((p2 ^ (r2&7))<<3));
    __syncthreads();
    gload16(Ahp + a1, LAh + g1*8);
    gload16(Ahp + a2, LAh + g2*8);
    gload16(Alp + a1, LAl + g1*8);
    gload16(Alp + a2, LAl + g2*8);
    gload16(Bhp + b1, LBh + g1*8);
    gload16(Bhp + b2, LBh + g2*8);
    gload16(Blp + b1, LBl + g1*8);
    gload16(Blp + b2, LBl + g2*8);
    __syncthreads();
    const int arow = w*16 + (lane&15);
    const int aswz = arow & 7;
    #pragma unroll
    for (int kk = 0; kk < 2; ++kk){
        const int ch = kk*4 + (lane>>4);
        short8 ah = *(const short8*)(LAh + arow*64 + ((ch ^ aswz)<<3));
        short8 al = *(const short8*)(LAl + arow*64 + ((ch ^ aswz)<<3));
        #pragma unroll
        for (int c = 0; c < 4; ++c){
            const int brow = c*16 + (lane&15);
            const int bo = brow*64 + ((ch ^ (brow&7))<<3);
            short8 bh = *(const short8*)(LBh + bo);
            short8 bl = *(const short8*)(LBl + bo);
            acc[c] = __builtin_amdgcn_mfma_f32_16x16x32_bf16(ah, bh, acc[c], 0,0,0);
            acc[c] = __builtin_amdgcn_mfma_f32_16x16x32_bf16(ah, bl, acc[c], 0,0,0);
            acc[c] = __builtin_amdgcn_mfma_f32_16x16x32_bf16(al, bh, acc[c], 0,0,0);
        }
    }
}

// small GEMM (K<=256): V3: out=aux-acc  V4: out=aux[col]-acc  V5: out=acc
template<int V>
__global__ __launch_bounds__(256) void k_mm(float* __restrict__ out,
        const u16* __restrict__ Ahp, const u16* __restrict__ Alp,
        const u16* __restrict__ Bhp, const u16* __restrict__ Blp,
        size_t sA, size_t sB, int nkt,
        const float* __restrict__ aux1){
    __shared__ u16 LAh[4096], LAl[4096], LBh[4096], LBl[4096];
    const int tid = threadIdx.x, lane = tid & 63, w = tid >> 6;
    const int j0 = blockIdx.x*64, i0 = blockIdx.y*64;
    float4v acc[4];
    #pragma unroll
    for (int c = 0; c < 4; ++c) acc[c] = (float4v){0.f,0.f,0.f,0.f};
    for (int kt = 0; kt < nkt; ++kt)
        mm_tile(Ahp, Alp, Bhp, Blp, sA, sB, i0, j0, kt*64, LAh, LAl, LBh, LBl, acc, lane, w);
    #pragma unroll
    for (int c = 0; c < 4; ++c)
        #pragma unroll
        for (int r = 0; r < 4; ++r){
            int grow = i0 + w*16 + (lane>>4)*4 + r;
            int gcol = j0 + c*16 + (lane&15);
            size_t idx = (size_t)grow*Ff + gcol;
            float v = acc[c][r];
            if constexpr (V == 3) out[idx] = aux1[idx] - v;
            if constexpr (V == 4) out[idx] = aux1[gcol] - v;
            if constexpr (V == 5) out[idx] = v;
        }
}

// Gram GEMM: G[256][256] += , K split over blockIdx.z (atomics)
__global__ __launch_bounds__(256) void k_gram_mm(float* __restrict__ G,
        const u16* __restrict__ Ahp, const u16* __restrict__ Alp,
        const u16* __restrict__ Bhp, const u16* __restrict__ Blp){
    __shared__ u16 LAh[4096], LAl[4096], LBh[4096], LBl[4096];
    const int tid = threadIdx.x, lane = tid & 63, w = tid >> 6;
    const int j0 = blockIdx.x*64, i0 = blockIdx.y*64, kb = blockIdx.z*256;
    float4v acc[4];
    #pragma unroll
    for (int c = 0; c < 4; ++c) acc[c] = (float4v){0.f,0.f,0.f,0.f};
    for (int kt = 0; kt < 4; ++kt)
        mm_tile(Ahp, Alp, Bhp, Blp, (size_t)Nn, (size_t)Nn, i0, j0, kb + kt*64, LAh, LAl, LBh, LBl, acc, lane, w);
    #pragma unroll
    for (int c = 0; c < 4; ++c)
        #pragma unroll
        for (int r = 0; r < 4; ++r){
            int grow = i0 + w*16 + (lane>>4)*4 + r;
            int gcol = j0 + c*16 + (lane&15);
            atomicAdd(&G[grow*Ff + gcol], acc[c][r]);
        }
}

// ---------------- big GEMM: BM=64, BN=256 (full width), K-split=8 planes ----------------
__global__ __launch_bounds__(512) void k_mmB(float* __restrict__ pb,
        const u16* __restrict__ Ahp, const u16* __restrict__ Alp,
        const u16* __restrict__ Bhp, const u16* __restrict__ Blp){
    __shared__ u16 LAh[4096], LAl[4096], LBh[16384], LBl[16384];
    const int tid = threadIdx.x, lane = tid & 63, w = tid >> 6;
    const int z = blockIdx.x, i0 = blockIdx.y*64;
    const int wr = w >> 2, wc = w & 3;
    float4v acc[2][4];
    #pragma unroll
    for (int m = 0; m < 2; ++m)
        #pragma unroll
        for (int n = 0; n < 4; ++n) acc[m][n] = (float4v){0.f,0.f,0.f,0.f};

    const int ra = tid >> 3, pa = tid & 7;
    const size_t aoff = (size_t)(i0+ra)*Nn + (size_t)((pa ^ (ra&7))<<3);

    for (int kt = 0; kt < 8; ++kt){
        const int k0 = z*512 + kt*64;
        __syncthreads();                      // LDS safe to overwrite
        gload16(Ahp + aoff + k0, LAh + tid*8);
        gload16(Alp + aoff + k0, LAl + tid*8);
        #pragma unroll
        for (int it = 0; it < 4; ++it){
            int g = it*512 + tid;
            int r = g >> 3, p = g & 7;
            size_t b = (size_t)r*Nn + (size_t)(k0 + ((p ^ (r&7))<<3));
            gload16(Bhp + b, LBh + g*8);
            gload16(Blp + b, LBl + g*8);
        }
        __syncthreads();                      // drains vmcnt before barrier
        #pragma unroll
        for (int kk = 0; kk < 2; ++kk){
            const int ch = kk*4 + (lane>>4);
            short8 ah0, ah1, al0, al1;
            {
                const int arow = wr*32 + (lane&15);
                const int ao = arow*64 + ((ch ^ (arow&7))<<3);
                ah0 = *(const short8*)(LAh + ao);
                al0 = *(const short8*)(LAl + ao);
            }
            {
                const int arow = wr*32 + 16 + (lane&15);
                const int ao = arow*64 + ((ch ^ (arow&7))<<3);
                ah1 = *(const short8*)(LAh + ao);
                al1 = *(const short8*)(LAl + ao);
            }
            #pragma unroll
            for (int n = 0; n < 4; ++n){
                const int bcol = wc*64 + n*16 + (lane&15);
                const int bo = bcol*64 + ((ch ^ (bcol&7))<<3);
                short8 bh = *(const short8*)(LBh + bo);
                short8 bl = *(const short8*)(LBl + bo);
                acc[0][n] = __builtin_amdgcn_mfma_f32_16x16x32_bf16(ah0, bh, acc[0][n], 0,0,0);
                acc[0][n] = __builtin_amdgcn_mfma_f32_16x16x32_bf16(ah0, bl, acc[0][n], 0,0,0);
                acc[0][n] = __builtin_amdgcn_mfma_f32_16x16x32_bf16(al0, bh, acc[0][n], 0,0,0);
                acc[1][n] = __builtin_amdgcn_mfma_f32_16x16x32_bf16(ah1, bh, acc[1][n], 0,0,0);
                acc[1][n] = __builtin_amdgcn_mfma_f32_16x16x32_bf16(ah1, bl, acc[1][n], 0,0,0);
                acc[1][n] = __builtin_amdgcn_mfma_f32_16x16x32_bf16(al1, bh, acc[1][n], 0,0,0);
            }
        }
    }
    float* op = pb + (size_t)z*NF;
    #pragma unroll
    for (int m = 0; m < 2; ++m)
        #pragma unroll
        for (int n = 0; n < 4; ++n)
            #pragma unroll
            for (int r = 0; r < 4; ++r){
                int row = i0 + wr*32 + m*16 + (lane>>4)*4 + r;
                int col = wc*64 + n*16 + (lane&15);
                op[(size_t)row*Ff + col] = acc[m][n][r];
            }
}

// reduce planes + epilogue.  V0: out+=s  V1: out-=s  V2: out=aux+0.5*sig(s) (+row split)  V3: out=aux-s
template<int V>
__global__ __launch_bounds__(256) void k_red(float* __restrict__ out, const float* __restrict__ pb,
                                             const float* __restrict__ aux, u16* __restrict__ oh,
                                             u16* __restrict__ ol){
    size_t i = (size_t)blockIdx.x*256 + threadIdx.x;
    float s = 0.f;
    #pragma unroll
    for (int zz = 0; zz < KS; ++zz) s += pb[(size_t)zz*NF + i];
    if constexpr (V == 0) out[i] += s;
    if constexpr (V == 1) out[i] -= s;
    if constexpr (V == 2){
        float v = aux[i] + 0.5f*(1.f/(1.f+expf(-s)));
        out[i] = v;
        u16 h = f2bf(v); oh[i] = h; ol[i] = f2bf(v - bfh(h));
    }
    if constexpr (V == 3) out[i] = aux[i] - s;
}

// ---------------- CSR sparse accumulators (one block per destination row) ----------------
__global__ __launch_bounds__(256) void k_csrT(float* __restrict__ t1, const float* __restrict__ y,
        const float* __restrict__ cc, const float* __restrict__ P,
        const int* __restrict__ rpI, const int* __restrict__ lI, const int* __restrict__ ej,
        const int* __restrict__ rpJ, const int* __restrict__ lJ, const int* __restrict__ ei,
        int useM){
    const int r = blockIdx.x, f = threadIdx.x;
    float acc = 0.f;
    const int b0 = rpI[r], b1 = rpI[r+1];
    for (int p = b0; p < b1; ++p){
        int e = lI[p];
        acc += cc[e] * y[(size_t)ej[e]*Ff + f];
    }
    if (useM){
        const int c0 = rpJ[r], c1 = rpJ[r+1];
        for (int p = c0; p < c1; ++p){
            int e = lJ[p];
            acc -= 0.5f * P[e] * y[(size_t)ei[e]*Ff + f];
        }
    }
    t1[(size_t)r*Ff + f] += acc;
}
__global__ __launch_bounds__(256) void k_csrZ(float* __restrict__ zn, const float* __restrict__ z,
        const float* __restrict__ cc,
        const int* __restrict__ rpI, const int* __restrict__ lI, const int* __restrict__ ej){
    const int r = blockIdx.x, f = threadIdx.x;
    float acc = 0.f;
    const int b0 = rpI[r], b1 = rpI[r+1];
    for (int p = b0; p < b1; ++p){
        int e = lI[p];
        acc += cc[e] * z[(size_t)ej[e]*Ff + f];
    }
    zn[(size_t)r*Ff + f] -= acc;
}

__global__ __launch_bounds__(256) void k_colsum(float* col, const float* __restrict__ y){
    int j = threadIdx.x;
    int r0 = blockIdx.x*64;
    float s = 0.f;
    for (int i = 0; i < 64; ++i) s += y[(size_t)(r0+i)*Ff + j];
    atomicAdd(&col[j], s);
}

// ---------------- per-edge kernels ----------------
__global__ __launch_bounds__(256) void k_p(float* __restrict__ P, const float* __restrict__ z,
        const int* __restrict__ ei, const int* __restrict__ ej, const float* __restrict__ ev){
    int e = blockIdx.x*4 + (threadIdx.x >> 6);
    int lane = threadIdx.x & 63;
    int i = ei[e], j = ej[e];
    float s = 0.f;
    #pragma unroll
    for (int q = 0; q < 4; ++q){
        int f = lane + q*64;
        float d = z[(size_t)i*Ff + f] - z[(size_t)j*Ff + f];
        s += d*d;
    }
    #pragma unroll
    for (int o = 32; o; o >>= 1) s += __shfl_xor(s, o);
    if (lane == 0) P[e] = sqrtf(s) * ev[e];
}
__global__ __launch_bounds__(256) void k_ep(float* __restrict__ c, const float* __restrict__ y,
        const int* __restrict__ ei, const int* __restrict__ ej, const float* __restrict__ ev,
        const float* __restrict__ V, const u32* __restrict__ slot){
    int e = blockIdx.x*4 + (threadIdx.x >> 6);
    int lane = threadIdx.x & 63;
    int i = ei[e], j = ej[e];
    float s = 0.f;
    #pragma unroll
    for (int q = 0; q < 4; ++q){
        int f = lane + q*64;
        s += y[(size_t)i*Ff + f] * y[(size_t)j*Ff + f];
    }
    #pragma unroll
    for (int o = 32; o; o >>= 1) s += __shfl_xor(s, o);
    if (lane == 0) c[e] = ev[e] * (s - 0.5f * V[slot[e]]);
}

// ---------------- head ----------------
__global__ __launch_bounds__(256) void k_head(float* __restrict__ out, const float* __restrict__ y,
                                              const float* __restrict__ z, const float* __restrict__ w2w,
                                              const float* __restrict__ w2b){
    const int node = blockIdx.x, t = threadIdx.x;
    float yv = y[(size_t)node*Ff + t], zv = z[(size_t)node*Ff + t];
    float yc = fminf(fmaxf(yv, -1e37f), 1e37f);
    float zc = fminf(fmaxf(zv, -1e37f), 1e37f);
    __shared__ float sy[256], sz[256];
    sy[t] = fabsf(yc); sz[t] = fabsf(zc);
    __syncthreads();
    for (int s = 128; s; s >>= 1){ if (t < s){ sy[t]=fmaxf(sy[t],sy[t+s]); sz[t]=fmaxf(sz[t],sz[t+s]); } __syncthreads(); }
    float my_ = fmaxf(sy[0], 1e-30f), mz_ = fmaxf(sz[0], 1e-30f);
    __syncthreads();
    float ysc = yc/my_, zsc = zc/mz_;
    sy[t] = ysc*ysc; sz[t] = zsc*zsc;
    __syncthreads();
    for (int s = 128; s; s >>= 1){ if (t < s){ sy[t]+=sy[t+s]; sz[t]+=sz[t+s]; } __syncthreads(); }
    float ny = fmaxf(my_*sqrtf(sy[0]), 1e-12f);
    float nz = fmaxf(mz_*sqrtf(sz[0]), 1e-12f);
    float ynv = yc/ny, znv = zc/nz;
    float acc[NCLS];
    #pragma unroll
    for (int cc = 0; cc < NCLS; ++cc)
        acc[cc] = znv*w2w[t*NCLS+cc] + ynv*w2w[(Ff+t)*NCLS+cc];
    __shared__ float red[NCLS][257];
    #pragma unroll
    for (int cc = 0; cc < NCLS; ++cc) red[cc][t] = acc[cc];
    __syncthreads();
    for (int s = 128; s; s >>= 1){
        if (t < s){
            #pragma unroll
            for (int cc = 0; cc < NCLS; ++cc) red[cc][t] += red[cc][t+s];
        }
        __syncthreads();
    }
    __shared__ float lg[NCLS];
    __shared__ float ml[2];
    if (t < NCLS) lg[t] = red[t][0] + w2b[t];
    __syncthreads();
    if (t == 0){
        float m = -1e30f;
        for (int cc = 0; cc < NCLS; ++cc) m = fmaxf(m, lg[cc]);
        float se = 0.f;
        for (int cc = 0; cc < NCLS; ++cc) se += expf(lg[cc]-m);
        ml[0] = m; ml[1] = logf(se);
    }
    __syncthreads();
    if (t < NCLS) out[(size_t)node*NCLS + t] = lg[t] - ml[0] - ml[1];
}

extern "C" void kernel_launch(void* const* d_in, const int* in_sizes, int n_in,
                              void* d_out, int out_size, void* d_ws, size_t ws_size,
                              hipStream_t stream){
    const float* feat = (const float*)d_in[0];
    const float* z0i  = (const float*)d_in[1];
    const float* w1p  = (const float*)d_in[2];
    const float* EAp  = (const float*)d_in[3];
    const float* w2w  = (const float*)d_in[4];
    const float* w2b  = (const float*)d_in[5];
    const float* w22p = (const float*)d_in[7];
    const float* evp  = (const float*)d_in[8];
    const int* ei   = (const int*)d_in[9];
    const int* ej   = (const int*)d_in[10];
    float* out = (float*)d_out;

    int ok = (n_in == 11) && (out_size == Nn*NCLS)
           && in_sizes[0]==NF && in_sizes[1]==NF && in_sizes[2]==NNx && in_sizes[3]==NNx
           && in_sizes[4]==2*Ff*NCLS && in_sizes[5]==NCLS && in_sizes[6]==NNx && in_sizes[7]==NNx
           && in_sizes[8]==Ne && in_sizes[9]==Ne && in_sizes[10]==Ne;
    if (!ok){
        k_fillc<<<(out_size+255)/256, 256, 0, stream>>>(out, -100.0f, out_size);
        return;
    }

    float *yA,*yB,*zA,*zB,*t1,*T1,*G,*col,*P,*cc,*hV,*pb; u32 *hK,*slot;
    int *cntI,*cntJ,*rpI,*rpJ,*fI,*fJ,*lI,*lJ;
    u16 *w1h,*w1l,*meh,*mel,*mth,*mtl,*xAh,*xAl,*xBh,*xBl,*x2h,*x2l,*yhA,*ylA,*yhB,*ylB,*gth,*gtl;
    hipGetSymbolAddress((void**)&yA,  HIP_SYMBOL(g_yA));
    hipGetSymbolAddress((void**)&yB,  HIP_SYMBOL(g_yB));
    hipGetSymbolAddress((void**)&zA,  HIP_SYMBOL(g_zA));
    hipGetSymbolAddress((void**)&zB,  HIP_SYMBOL(g_zB));
    hipGetSymbolAddress((void**)&t1,  HIP_SYMBOL(g_t1));
    hipGetSymbolAddress((void**)&T1,  HIP_SYMBOL(g_T1));
    hipGetSymbolAddress((void**)&G,   HIP_SYMBOL(g_G));
    hipGetSymbolAddress((void**)&col, HIP_SYMBOL(g_col));
    hipGetSymbolAddress((void**)&P,   HIP_SYMBOL(g_P));
    hipGetSymbolAddress((void**)&cc,  HIP_SYMBOL(g_cc));
    hipGetSymbolAddress((void**)&hV,  HIP_SYMBOL(g_hV));
    hipGetSymbolAddress((void**)&pb,  HIP_SYMBOL(g_pb));
    hipGetSymbolAddress((void**)&hK,  HIP_SYMBOL(g_hK));
    hipGetSymbolAddress((void**)&slot,HIP_SYMBOL(g_slot));
    hipGetSymbolAddress((void**)&cntI,HIP_SYMBOL(g_cntI));
    hipGetSymbolAddress((void**)&cntJ,HIP_SYMBOL(g_cntJ));
    hipGetSymbolAddress((void**)&rpI, HIP_SYMBOL(g_rpI));
    hipGetSymbolAddress((void**)&rpJ, HIP_SYMBOL(g_rpJ));
    hipGetSymbolAddress((void**)&fI,  HIP_SYMBOL(g_fI));
    hipGetSymbolAddress((void**)&fJ,  HIP_SYMBOL(g_fJ));
    hipGetSymbolAddress((void**)&lI,  HIP_SYMBOL(g_lI));
    hipGetSymbolAddress((void**)&lJ,  HIP_SYMBOL(g_lJ));
    hipGetSymbolAddress((void**)&w1h, HIP_SYMBOL(g_w1h));
    hipGetSymbolAddress((void**)&w1l, HIP_SYMBOL(g_w1l));
    hipGetSymbolAddress((void**)&meh, HIP_SYMBOL(g_meh));
    hipGetSymbolAddress((void**)&mel, HIP_SYMBOL(g_mel));
    hipGetSymbolAddress((void**)&mth, HIP_SYMBOL(g_mth));
    hipGetSymbolAddress((void**)&mtl, HIP_SYMBOL(g_mtl));
    hipGetSymbolAddress((void**)&xAh, HIP_SYMBOL(g_xAh));
    hipGetSymbolAddress((void**)&xAl, HIP_SYMBOL(g_xAl));
    hipGetSymbolAddress((void**)&xBh, HIP_SYMBOL(g_xBh));
    hipGetSymbolAddress((void**)&xBl, HIP_SYMBOL(g_xBl));
    hipGetSymbolAddress((void**)&x2h, HIP_SYMBOL(g_x2h));
    hipGetSymbolAddress((void**)&x2l, HIP_SYMBOL(g_x2l));
    hipGetSymbolAddress((void**)&yhA, HIP_SYMBOL(g_yhA));
    hipGetSymbolAddress((void**)&ylA, HIP_SYMBOL(g_ylA));
    hipGetSymbolAddress((void**)&yhB, HIP_SYMBOL(g_yhB));
    hipGetSymbolAddress((void**)&ylB, HIP_SYMBOL(g_ylB));
    hipGetSymbolAddress((void**)&gth, HIP_SYMBOL(g_gth));
    hipGetSymbolAddress((void**)&gtl, HIP_SYMBOL(g_gtl));

    const dim3 gG(Ff/64, Nn/64);     // small k_mm grid (4,64)
    const dim3 gXT(Ff/64, Nn/64);
    const dim3 gME(Nn/64, Nn/64);
    const dim3 gGT(Ff/64, Ff/64);
    const dim3 gGram(4, 4, 16);
    const dim3 gB(KS, Nn/64);        // big GEMM (8,64)

    // ---- startup: splits, copies, hash, CSR ----
    k_split  <<<NNx/256, 256, 0, stream>>>(w1h, w1l, w1p);
    k_splitME2<<<gME, 256, 0, stream>>>(meh, mel, mth, mtl, EAp, w22p);
    k_copy<<<NF/256, 256, 0, stream>>>(yA, feat, NF);
    k_copy<<<NF/256, 256, 0, stream>>>(zA, z0i, NF);
    k_copy<<<Ne/256, 256, 0, stream>>>(cc, evp, Ne);
    k_split  <<<NF/256, 256, 0, stream>>>(yhA, ylA, yA);
    k_splitXT<<<gXT, 256, 0, stream>>>(xAh, xAl, yA);
    k_hkeys_clear<<<TSZ/256, 256, 0, stream>>>(hK);
    k_hsetup<<<Ne/256, 256, 0, stream>>>(hK, slot, ei, ej);
    k_zeroi<<<Nn/256, 256, 0, stream>>>(cntI, Nn);
    k_zeroi<<<Nn/256, 256, 0, stream>>>(cntJ, Nn);
    k_count<<<Ne/256, 256, 0, stream>>>(cntI, cntJ, ei, ej);
    k_scan<<<1, 1024, 0, stream>>>(cntI, rpI);
    k_scan<<<1, 1024, 0, stream>>>(cntJ, rpJ);
    k_zeroi<<<Nn/256, 256, 0, stream>>>(fI, Nn);
    k_zeroi<<<Nn/256, 256, 0, stream>>>(fJ, Nn);
    k_fillcsr<<<Ne/256, 256, 0, stream>>>(rpI, rpJ, fI, fJ, lI, lJ, ei, ej);

    float *y = yA, *yn = yB, *z = zA, *zn = zB;
    for (int t = 1; t <= 4; ++t){
        // G = y^T y
        k_zero<<<Ff*Ff/256, 256, 0, stream>>>(G, Ff*Ff);
        k_gram_mm<<<gGram, 256, 0, stream>>>(G, xAh, xAl, xAh, xAl);
        k_splitGT<<<gGT, 256, 0, stream>>>(gth, gtl, G);
        // t1 = base - y@G
        if (t == 1){
            k_zero<<<1, 256, 0, stream>>>(col, Ff);
            k_colsum<<<64, 256, 0, stream>>>(col, y);
            k_mm<4><<<gG, 256, 0, stream>>>(t1, yhA, ylA, gth, gtl, (size_t)Ff, (size_t)Ff, 4, col);
        } else {
            k_mm<3><<<gG, 256, 0, stream>>>(t1, yhA, ylA, gth, gtl, (size_t)Ff, (size_t)Ff, 4, T1);
        }
        // sparse additions (CSR, one block per row)
        k_csrT<<<Nn, 256, 0, stream>>>(t1, y, cc, P, rpI, lI, ej, rpJ, lJ, ei, (t >= 2) ? 1 : 0);
        // t1 += mEA@y ; t1 -= mEA^T@y
        k_mmB<<<gB, 512, 0, stream>>>(pb, meh, mel, xAh, xAl);
        k_red<0><<<NF/256, 256, 0, stream>>>(t1, pb, nullptr, nullptr, nullptr);
        if (t >= 2){
            k_mmB<<<gB, 512, 0, stream>>>(pb, mth, mtl, xAh, xAl);
            k_red<1><<<NF/256, 256, 0, stream>>>(t1, pb, nullptr, nullptr, nullptr);
        }
        // yn = feat + 0.5*sigmoid(w1@t1)  (+ fused row split of yn)
        k_splitXT<<<gXT, 256, 0, stream>>>(x2h, x2l, t1);
        k_mmB<<<gB, 512, 0, stream>>>(pb, w1h, w1l, x2h, x2l);
        k_red<2><<<NF/256, 256, 0, stream>>>(yn, pb, feat, yhB, ylB);
        // zn = z - mEA@z - sparse
        k_splitXT<<<gXT, 256, 0, stream>>>(x2h, x2l, z);
        k_mmB<<<gB, 512, 0, stream>>>(pb, meh, mel, x2h, x2l);
        k_red<3><<<NF/256, 256, 0, stream>>>(zn, pb, z, nullptr, nullptr);
        k_csrZ<<<Nn, 256, 0, stream>>>(zn, z, cc, rpI, lI, ej);
        // prepare next layer
        if (t < 4){
            k_p<<<Ne/4, 256, 0, stream>>>(P, z, ei, ej, evp);
            k_zero<<<TSZ/256, 256, 0, stream>>>(hV, TSZ);
            k_hacc<<<Ne/256, 256, 0, stream>>>(hV, P, slot);
            k_ep<<<Ne/4, 256, 0, stream>>>(cc, y, ei, ej, evp, hV, slot);
            k_splitXT<<<gXT, 256, 0, stream>>>(xBh, xBl, yn);     // yn^T (becomes next y^T)
            k_zero<<<Ff*Ff/256, 256, 0, stream>>>(G, Ff*Ff);
            k_gram_mm<<<gGram, 256, 0, stream>>>(G, xAh, xAl, xBh, xBl);   // y^T yn
            k_splitGT<<<gGT, 256, 0, stream>>>(gth, gtl, G);
            k_mm<5><<<gG, 256, 0, stream>>>(T1, yhA, ylA, gth, gtl, (size_t)Ff, (size_t)Ff, 4, nullptr);
        }
        float* tmp;
        tmp = y; y = yn; yn = tmp;
        tmp = z; z = zn; zn = tmp;
        u16* tu;
        tu = xAh; xAh = xBh; xBh = tu;
        tu = xAl; xAl = xBl; xBl = tu;
        tu = yhA; yhA = yhB; yhB = tu;
        tu = ylA; ylA = ylB; ylB = tu;
    }
    k_head<<<Nn, 256, 0, stream>>>(out, y, z, w2w, w2b);
}